// Round 5
// baseline (2533.295 us; speedup 1.0000x reference)
//
#include <hip/hip_runtime.h>

#define N_    64
#define C_    64
#define T_    300
#define V_    25
#define IC_   16
#define TV_   7500      // T*V
#define CTV_  480000    // C*T*V  (per-n x slice)
#define NB_   6400      // mega grid blocks (100 x 64)

typedef __attribute__((ext_vector_type(8))) short short8;
typedef __attribute__((ext_vector_type(4))) short short4v;
typedef __attribute__((ext_vector_type(4))) float f32x4;

static __device__ inline short f2bf(float f) {
    unsigned u = __float_as_uint(f);
    unsigned r = (u + 0x7fff + ((u >> 16) & 1)) >> 16;
    return (short)r;
}

// ---------------- A_mix: Chebyshev mix + column softmax ----------------
__global__ void amix_kernel(const float* __restrict__ A, const float* __restrict__ w,
                            float* __restrict__ amix) {
    int tid = threadIdx.x;
    if (tid >= 75) return;
    int s = tid / 25, col = tid % 25;
    const float* As = A + s * 625;
    float av[25], ch4[25];
#pragma unroll
    for (int r = 0; r < 25; ++r) {
        float a = As[r * 25 + col];
        float a2 = a * a;
        float eye = (r == col) ? 1.f : 0.f;
        av[r] = a;
        ch4[r] = 8.f * a2 * a2 - 8.f * a2 + eye;
    }
    float m = -1e30f;
#pragma unroll
    for (int r = 0; r < 25; ++r) m = fmaxf(m, ch4[r] * (1.f / 25.f));
    float e[25];
    float sum = 0.f;
#pragma unroll
    for (int r = 0; r < 25; ++r) { e[r] = __expf(ch4[r] * (1.f / 25.f) - m); sum += e[r]; }
    float inv = 1.f / sum;
    float w0 = w[0], w1 = w[1], w2 = w[2], w3 = w[3], w4 = w[4];
#pragma unroll
    for (int r = 0; r < 25; ++r) {
        float a = av[r], a2 = a * a;
        float eye = (r == col) ? 1.f : 0.f;
        amix[s * 625 + r * 25 + col] =
            w0 * a + w1 * (e[r] * inv) + w2 * ch4[r] +
            w3 * (4.f * a2 * a - 3.f * a) + w4 * (2.f * a2 - eye);
    }
}

// ---------------- prep_all: pack pair weights + dw A-frags + biases ----------------
struct PrepArgs {
    const float* w[9][2];   // pairs 0..4 taps1, 5..8 taps9
    const float* b[9][2];
    const float* dw;
    const float* db;
};

__global__ __launch_bounds__(256) void prep_all(
    PrepArgs pa, short* __restrict__ wpkA, short* __restrict__ wpkB,
    short* __restrict__ dwpk, float* __restrict__ bpk, float* __restrict__ db_sum) {
    int idx = blockIdx.x * 256 + threadIdx.x;
    if (idx < 83968) {
        int pair, within, taps;
        short* dst;
        if (idx < 10240) {
            pair = idx / 2048;
            within = idx - pair * 2048;
            taps = 1;
            dst = wpkA + idx;
        } else {
            int idx2 = idx - 10240;
            int qp = idx2 / 18432;
            pair = 5 + qp;
            within = idx2 - qp * 18432;
            taps = 9;
            dst = wpkB + idx2;
        }
        int j = within & 7;
        int l = (within >> 3) & 63;
        int half = (within >> 9) & 1;
        int kk = within >> 10;
        int K = kk * 32 + ((l >> 4) << 3) + j;
        int c = K & 63, k = K >> 6;
        int o = l & 15;
        *dst = f2bf(pa.w[pair][half][(o * 64 + c) * taps + k]);
    } else if (idx < 96256) {
        int idx3 = idx - 83968;
        int j = idx3 & 7;
        int lane = (idx3 >> 3) & 63;
        int kk = (idx3 >> 9) & 1;
        int mt = idx3 >> 10;
        int R = mt * 16 + (lane & 15);
        int c = kk * 32 + ((lane >> 4) << 3) + j;
        int i = R >> 6, o = R & 63;
        dwpk[idx3] = f2bf(pa.dw[i * 4096 + o * 64 + c]);
    } else if (idx < 96544) {
        int idx4 = idx - 96256;
        int pairG = idx4 >> 5;
        int half = (idx4 >> 4) & 1;
        int o = idx4 & 15;
        bpk[idx4] = pa.b[pairG][half][o];
    } else if (idx < 96608) {
        int o = idx - 96544;
        db_sum[o] = pa.db[o] + pa.db[64 + o] + pa.db[128 + o];
    }
}

// ---------------- fused conv pair + gram + softmax per (n, pair) ----------------
// taps1: chunk=250 pos (10 t-rows), taps9: chunk=125 (5 t-rows, halo 4 rows each side)
template <int TAPS>
__global__ __launch_bounds__(256) void pair_gram(
    const float* __restrict__ x, const short* __restrict__ wpkG,
    const float* __restrict__ bpk, int pairG0, float* __restrict__ S) {
    constexpr int CH   = (TAPS == 1) ? 250 : 125;   // positions per chunk
    constexpr int NTW  = (TAPS == 1) ? 4 : 2;       // 16-wide n-tiles per wave
    constexpr int ROWS = (TAPS == 1) ? 256 : 328;   // staged x rows
    constexpr int H25  = (TAPS / 2) * 25;           // halo rows
    constexpr int KT   = (CH / 25) * 16;            // gram K per chunk (160 / 80)
    constexpr int KS   = (TAPS == 1) ? 5 : 3;       // 32-wide K steps (pad 80->96)
    constexpr int FSTR = (TAPS == 1) ? 168 : 104;   // fT row stride (shorts)
    constexpr int NCH  = 7500 / CH;                 // chunks (30 / 60)

    __shared__ __align__(16) short xs[ROWS * 72];
    __shared__ __align__(16) short fT[2][32 * FSTR];
    __shared__ float sm[32 * 36];

    int tid = threadIdx.x;
    int n = blockIdx.x;
    int pr = blockIdx.y;
    int wave = tid >> 6, lane = tid & 63;
    int q = lane >> 4, m = lane & 15;

    const float* xn = x + n * CTV_;
    const short* wb = wpkG + pr * (TAPS * 2048);
    const float* bp = bpk + (pairG0 + pr) * 32;

    // zero fT once (pad rows 25..31 and K-pad columns stay zero)
    {
        int* fz = (int*)fT;
        for (int jj = tid; jj < 32 * FSTR; jj += 256) fz[jj] = 0;
    }
    float b1r[4], b2r[4];
#pragma unroll
    for (int r = 0; r < 4; ++r) {
        b1r[r] = bp[q * 4 + r];
        b2r[r] = bp[16 + q * 4 + r];
    }

    int qm = wave >> 1, qn = wave & 1;
    f32x4 sacc = (f32x4)(0.f);

    for (int ch = 0; ch < NCH; ++ch) {
        int pos0 = ch * CH - H25;
        // stage x chunk (+halo) as [row][c] bf16
        for (int jj = tid; jj < 64 * ROWS; jj += 256) {
            int c = jj / ROWS;
            int rr = jj - c * ROWS;
            int pp = pos0 + rr;
            float v = (pp >= 0 && pp < TV_) ? xn[c * TV_ + pp] : 0.f;
            xs[rr * 72 + c] = f2bf(v);
        }
        __syncthreads();

        // conv: f{1,2}[o][p] = sum_{c,k} W[o,c,k] x[c, p+(k-T/2)*25]
        f32x4 acc[2][NTW];
#pragma unroll
        for (int h = 0; h < 2; ++h)
#pragma unroll
            for (int nt = 0; nt < NTW; ++nt) acc[h][nt] = (f32x4)(0.f);

#pragma unroll
        for (int kk = 0; kk < 2 * TAPS; ++kk) {
            int k = kk >> 1;
            int c0 = (kk & 1) * 32;
            short8 af0 = *(const short8*)(wb + (kk * 2 + 0) * 512 + lane * 8);
            short8 af1 = *(const short8*)(wb + (kk * 2 + 1) * 512 + lane * 8);
#pragma unroll
            for (int nt = 0; nt < NTW; ++nt) {
                int rbase = H25 + (wave * NTW + nt) * 16 + m + (k - TAPS / 2) * 25;
                short8 bf = *(const short8*)(xs + rbase * 72 + c0 + q * 8);
                acc[0][nt] = __builtin_amdgcn_mfma_f32_16x16x32_bf16(af0, bf, acc[0][nt], 0, 0, 0);
                acc[1][nt] = __builtin_amdgcn_mfma_f32_16x16x32_bf16(af1, bf, acc[1][nt], 0, 0, 0);
            }
        }
        // write f chunk to LDS transposed: fT[h][v][trow*16 + o] (bias added)
#pragma unroll
        for (int h = 0; h < 2; ++h) {
#pragma unroll
            for (int nt = 0; nt < NTW; ++nt) {
                int p = (wave * NTW + nt) * 16 + m;
                if (p < CH) {
                    int trow = p / 25;
                    int v = p - trow * 25;
                    short4v pk;
#pragma unroll
                    for (int r = 0; r < 4; ++r)
                        pk[r] = f2bf(acc[h][nt][r] + (h ? b2r[r] : b1r[r]));
                    *(short4v*)(&fT[h][v * FSTR + trow * 16 + q * 4]) = pk;
                }
            }
        }
        __syncthreads();

        // gram accumulate: wave owns quadrant (qm, qn) of S
#pragma unroll
        for (int ks = 0; ks < KS; ++ks) {
            short8 a = *(const short8*)(&fT[0][(qm * 16 + m) * FSTR + ks * 32 + q * 8]);
            short8 b = *(const short8*)(&fT[1][(qn * 16 + m) * FSTR + ks * 32 + q * 8]);
            sacc = __builtin_amdgcn_mfma_f32_16x16x32_bf16(a, b, sacc, 0, 0, 0);
        }
    }

    // write quadrant to sm
#pragma unroll
    for (int r = 0; r < 4; ++r) {
        int v1 = qm * 16 + q * 4 + r;
        int v2 = qn * 16 + m;
        sm[v1 * 36 + v2] = sacc[r];
    }
    __syncthreads();

    // column softmax (axis -2), scale 1/4800
    if (tid < 25) {
        constexpr int smapA[5] = {0, 2, 3, 6, 8};
        constexpr int smapB[4] = {1, 4, 5, 7};
        int slab = (TAPS == 1) ? smapA[pr] : smapB[pr];
        int col = tid;
        float mx = -1e30f;
#pragma unroll
        for (int r = 0; r < 25; ++r) mx = fmaxf(mx, sm[r * 36 + col] * (1.f / 4800.f));
        float e[25];
        float sum = 0.f;
#pragma unroll
        for (int r = 0; r < 25; ++r) {
            e[r] = __expf(sm[r * 36 + col] * (1.f / 4800.f) - mx);
            sum += e[r];
        }
        float inv = 1.f / sum;
        float* Sd = S + slab * 40000 + n * 625;
#pragma unroll
        for (int r = 0; r < 25; ++r) Sd[r * 25 + col] = e[r] * inv;
    }
}

// ---------------- mega: y = sum_i (dw_i @ x) @ Ai, all subsets, + BN partials ----------------
__global__ __launch_bounds__(256) void mega(
    const float* __restrict__ x, const float* __restrict__ amix,
    const float* __restrict__ S, const float* __restrict__ wts,
    const short* __restrict__ dwpk, const float* __restrict__ db_sum,
    float* __restrict__ out, float* __restrict__ partials) {
    __shared__ __align__(16) short xs[80 * 72];       // [p][c] bf16, stride 72
    __shared__ __align__(16) short us[3 * 64 * 104];  // [t][o][K=96 pad 104] bf16
    __shared__ __align__(16) short Aib[3 * 32 * 40];  // [i][v][vp pad 40] bf16

    int tid = threadIdx.x;
    int n = blockIdx.y;
    int t0 = blockIdx.x * 3;
    const float* xn = x + n * CTV_ + t0 * 25;

    for (int jj = tid; jj < 64 * 80; jj += 256) {
        int c = jj / 80, p = jj - c * 80;
        float v = (p < 75) ? xn[c * TV_ + p] : 0.f;
        xs[p * 72 + c] = f2bf(v);
    }
    for (int jj = tid; jj < 3 * 64 * 52; jj += 256) ((int*)us)[jj] = 0;
    float w5 = wts[5], w6 = wts[6], w7 = wts[7];
    for (int jj = tid; jj < 3840; jj += 256) {
        int i = jj / 1280;
        int rem = jj - i * 1280;
        int v = rem / 40, vp = rem - v * 40;
        float val = 0.f;
        if (v < 25 && vp < 25) {
            int e = vp * 25 + v;
            val = amix[i * 625 + e]
                + w5 * S[(i * 3 + 0) * 40000 + n * 625 + e]
                + w6 * S[(i * 3 + 1) * 40000 + n * 625 + e]
                + w7 * S[(i * 3 + 2) * 40000 + n * 625 + e];
        }
        Aib[jj] = f2bf(val);
    }

    int wave = tid >> 6, lane = tid & 63;
    int q = lane >> 4, m = lane & 15;

    short8 af[3][2];
#pragma unroll
    for (int mt = 0; mt < 3; ++mt)
#pragma unroll
        for (int kk = 0; kk < 2; ++kk)
            af[mt][kk] = *(const short8*)(dwpk + ((wave * 3 + mt) * 2 + kk) * 512 + lane * 8);
    float db4[4];
#pragma unroll
    for (int r = 0; r < 4; ++r) db4[r] = db_sum[wave * 16 + q * 4 + r];

    __syncthreads();

    f32x4 acc[3][5];
#pragma unroll
    for (int mt = 0; mt < 3; ++mt)
#pragma unroll
        for (int nt = 0; nt < 5; ++nt) acc[mt][nt] = (f32x4)(0.f);

#pragma unroll
    for (int nt = 0; nt < 5; ++nt) {
        short8 b0 = *(const short8*)(xs + (nt * 16 + m) * 72 + q * 8);
        short8 b1 = *(const short8*)(xs + (nt * 16 + m) * 72 + 32 + q * 8);
#pragma unroll
        for (int mt = 0; mt < 3; ++mt) {
            acc[mt][nt] = __builtin_amdgcn_mfma_f32_16x16x32_bf16(af[mt][0], b0, acc[mt][nt], 0, 0, 0);
            acc[mt][nt] = __builtin_amdgcn_mfma_f32_16x16x32_bf16(af[mt][1], b1, acc[mt][nt], 0, 0, 0);
        }
    }
#pragma unroll
    for (int nt = 0; nt < 5; ++nt) {
        int p = nt * 16 + m;
        if (p < 75) {
            int t = p / 25, vp = p - t * 25;
            int base = t * 6656 + vp;
#pragma unroll
            for (int mt = 0; mt < 3; ++mt) {
#pragma unroll
                for (int r = 0; r < 4; ++r) {
                    int R = wave * 48 + mt * 16 + q * 4 + r;
                    int i = R >> 6, o = R & 63;
                    us[base + o * 104 + i * 32] = f2bf(acc[mt][nt][r]);
                }
            }
        }
    }
    __syncthreads();

    short8 bfr[3][2];
#pragma unroll
    for (int i = 0; i < 3; ++i)
#pragma unroll
        for (int nt = 0; nt < 2; ++nt)
            bfr[i][nt] = *(const short8*)(Aib + (i * 32 + nt * 16 + m) * 40 + q * 8);

    float sr[4] = {0.f, 0.f, 0.f, 0.f}, s2r[4] = {0.f, 0.f, 0.f, 0.f};
    float* yb = out + n * CTV_ + t0 * 25;
#pragma unroll
    for (int t = 0; t < 3; ++t) {
        f32x4 a2[2];
        a2[0] = (f32x4)(0.f);
        a2[1] = (f32x4)(0.f);
#pragma unroll
        for (int i = 0; i < 3; ++i) {
            short8 ua = *(const short8*)(us + t * 6656 + (wave * 16 + m) * 104 + i * 32 + q * 8);
            a2[0] = __builtin_amdgcn_mfma_f32_16x16x32_bf16(ua, bfr[i][0], a2[0], 0, 0, 0);
            a2[1] = __builtin_amdgcn_mfma_f32_16x16x32_bf16(ua, bfr[i][1], a2[1], 0, 0, 0);
        }
#pragma unroll
        for (int nt = 0; nt < 2; ++nt) {
            int v = nt * 16 + m;
            if (v < 25) {
#pragma unroll
                for (int r = 0; r < 4; ++r) {
                    int o = wave * 16 + q * 4 + r;
                    float val = a2[nt][r] + db4[r];
                    yb[o * TV_ + t * 25 + v] = val;
                    sr[r] += val;
                    s2r[r] += val * val;
                }
            }
        }
    }

    int bid = blockIdx.y * 100 + blockIdx.x;
#pragma unroll
    for (int r = 0; r < 4; ++r) {
        float s = sr[r], s2 = s2r[r];
#pragma unroll
        for (int d = 1; d < 16; d <<= 1) {
            s += __shfl_xor(s, d, 64);
            s2 += __shfl_xor(s2, d, 64);
        }
        if (m == 0) {
            int o = wave * 16 + q * 4 + r;
            partials[o * NB_ + bid] = s;
            partials[(64 + o) * NB_ + bid] = s2;
        }
    }
}

// ---------------- BN stats: sum partials ----------------
__global__ __launch_bounds__(256) void bn_stats(const float* __restrict__ partials,
                                                float* __restrict__ stats) {
    int j = blockIdx.x;
    int tid = threadIdx.x;
    float s = 0.f;
    for (int idx = tid; idx < NB_; idx += 256) s += partials[j * NB_ + idx];
    for (int d = 32; d > 0; d >>= 1) s += __shfl_down(s, d, 64);
    __shared__ float ls[4];
    if ((tid & 63) == 0) ls[tid >> 6] = s;
    __syncthreads();
    if (tid == 0) stats[j] = ls[0] + ls[1] + ls[2] + ls[3];
}

// ---------------- BN apply + residual + relu (in place on y) ----------------
__global__ __launch_bounds__(256) void bn_final(
    const float* __restrict__ x, const float* __restrict__ stats,
    const float* __restrict__ bnw, const float* __restrict__ bnb,
    float* __restrict__ y) {
    int pi = blockIdx.x * 256 + threadIdx.x;
    int o = (pi / TV_) & 63;
    const float cnt = (float)(N_ * TV_);
    float mu = stats[o] / cnt;
    float var = stats[64 + o] / cnt - mu * mu;
    float inv = rsqrtf(var + 1e-5f);
    float val = (y[pi] - mu) * inv * bnw[o] + bnb[o] + x[pi];
    y[pi] = fmaxf(val, 0.f);
}

extern "C" void kernel_launch(void* const* d_in, const int* in_sizes, int n_in,
                              void* d_out, int out_size, void* d_ws, size_t ws_size,
                              hipStream_t stream) {
    (void)in_sizes; (void)n_in; (void)out_size; (void)ws_size;
    const float* x     = (const float*)d_in[0];
    const float* wts   = (const float*)d_in[1];
    const float* A     = (const float*)d_in[2];
    const float* a_w   = (const float*)d_in[3];
    const float* a_b   = (const float*)d_in[4];
    const float* b_w   = (const float*)d_in[5];
    const float* b_b   = (const float*)d_in[6];
    const float* d_wp  = (const float*)d_in[7];
    const float* d_bp  = (const float*)d_in[8];
    const float* t1_w  = (const float*)d_in[9];
    const float* t1_b  = (const float*)d_in[10];
    const float* t2_w  = (const float*)d_in[11];
    const float* t2_b  = (const float*)d_in[12];
    const float* st11_w1 = (const float*)d_in[13];
    const float* st11_w9 = (const float*)d_in[14];
    const float* st11_b  = (const float*)d_in[15];
    const float* st12_w1 = (const float*)d_in[16];
    const float* st12_w9 = (const float*)d_in[17];
    const float* st12_b  = (const float*)d_in[18];
    const float* bn_w  = (const float*)d_in[19];
    const float* bn_b  = (const float*)d_in[20];
    float* out = (float*)d_out;

    // ---- workspace layout (all disjoint, total < 6 MB) ----
    char* ws = (char*)d_ws;
    float* amix   = (float*)(ws);              // [0, 7500)
    float* stats  = (float*)(ws + 8192);       // 128 f
    float* db_sum = (float*)(ws + 12288);      // 64 f
    float* bpk    = (float*)(ws + 13312);      // 288 f
    float* S      = (float*)(ws + 16384);      // 9 * 40000 f -> ends 1,456,384
    short* wpkA   = (short*)(ws + 1572864);    // 10240 bf16 -> ends 1,593,344
    short* wpkB   = (short*)(ws + 1605632);    // 73728 bf16 -> ends 1,753,088
    short* dwpk   = (short*)(ws + 1769472);    // 12288 bf16 -> ends 1,794,048
    float* partials = (float*)(ws + 2097152);  // 128*6400 f -> ends 5,373,952

    amix_kernel<<<1, 128, 0, stream>>>(A, wts, amix);

    PrepArgs pa;
    // taps-1 pairs: (i0 a/b), (i0 st), (i1 a/b), (i2 a/b), (i2 st)
    pa.w[0][0] = a_w;            pa.w[0][1] = b_w;
    pa.w[1][0] = st11_w1;        pa.w[1][1] = st12_w1;
    pa.w[2][0] = a_w + 1024;     pa.w[2][1] = b_w + 1024;
    pa.w[3][0] = a_w + 2048;     pa.w[3][1] = b_w + 2048;
    pa.w[4][0] = st11_w1 + 1024; pa.w[4][1] = st12_w1 + 1024;
    // taps-9 pairs: (i0 t), (i1 t), (i1 st), (i2 t)
    pa.w[5][0] = t1_w;           pa.w[5][1] = t2_w;
    pa.w[6][0] = t1_w + 9216;    pa.w[6][1] = t2_w + 9216;
    pa.w[7][0] = st11_w9;        pa.w[7][1] = st12_w9;
    pa.w[8][0] = t1_w + 18432;   pa.w[8][1] = t2_w + 18432;
    pa.b[0][0] = a_b;            pa.b[0][1] = b_b;
    pa.b[1][0] = st11_b;         pa.b[1][1] = st12_b;
    pa.b[2][0] = a_b + 16;       pa.b[2][1] = b_b + 16;
    pa.b[3][0] = a_b + 32;       pa.b[3][1] = b_b + 32;
    pa.b[4][0] = st11_b + 32;    pa.b[4][1] = st12_b + 32;
    pa.b[5][0] = t1_b;           pa.b[5][1] = t2_b;
    pa.b[6][0] = t1_b + 16;      pa.b[6][1] = t2_b + 16;
    pa.b[7][0] = st11_b + 16;    pa.b[7][1] = st12_b + 16;
    pa.b[8][0] = t1_b + 32;      pa.b[8][1] = t2_b + 32;
    pa.dw = d_wp;
    pa.db = d_bp;

    prep_all<<<378, 256, 0, stream>>>(pa, wpkA, wpkB, dwpk, bpk, db_sum);

    pair_gram<1><<<dim3(64, 5), 256, 0, stream>>>(x, wpkA, bpk, 0, S);
    pair_gram<9><<<dim3(64, 4), 256, 0, stream>>>(x, wpkB, bpk, 5, S);

    mega<<<dim3(100, 64), 256, 0, stream>>>(x, amix, S, wts, dwpk, db_sum, out, partials);
    bn_stats<<<128, 256, 0, stream>>>(partials, stats);
    bn_final<<<120000, 256, 0, stream>>>(x, stats, bn_w, bn_b, out);
}